// Round 5
// baseline (390.985 us; speedup 1.0000x reference)
//
#include <hip/hip_runtime.h>
#include <cmath>

// ---------------------------------------------------------------------------
// GraphTransformerLayer on MI355X (gfx950).
// N=50000 nodes, C=128, H=8 heads, D=16, E=800000 edges (+N self loops).
//
// Pipeline (12 dispatches):
//   zero -> CSR build (count/scan x3/fill)      [edge_index arrives as INT32]
//   k_cast x->bf16 ; k_prep weights -> bf16 [Cout][K]
//   k_gemm128<0>: QKV (grid.y=3)                -> qkv bf16 [N][384]
//   k_attn: 1 wave/dest node, 4-edge batches    -> ob bf16
//   k_gemm128<2>: Wo + bias + resid + LN1       -> x1f fp32, x1b bf16
//   k_ffn: FFN1 + gelu + FFN2 + resid + LN2     -> d_out fp32 (hb eliminated)
//
// GEMM structure: A tile (128x128 bf16, 32KB) staged once via global_load_lds
// width=16 with XOR swizzle (chunk ^ row&7) on the global side; ONE barrier;
// B-fragments streamed directly from global (weights are L2-hot, every block
// reads the same 32-256KB). 64 MFMA 16x16x32 per wave (64x64 tile).
// k_ffn: h chunk round-trips through a 32KB LDS tile (C-layout -> A-layout).
// ---------------------------------------------------------------------------

typedef short bf16x8 __attribute__((ext_vector_type(8)));
typedef float f32x4 __attribute__((ext_vector_type(4)));
typedef unsigned int uint_as1 __attribute__((address_space(1)));
typedef unsigned int uint_as3 __attribute__((address_space(3)));

__device__ inline unsigned short f2bf(float f) {
    unsigned int u = __float_as_uint(f);
    u += 0x7fffu + ((u >> 16) & 1u);   // round-to-nearest-even
    return (unsigned short)(u >> 16);
}
__device__ inline float bflo(unsigned int w) { return __uint_as_float(w << 16); }
__device__ inline float bfhi(unsigned int w) { return __uint_as_float(w & 0xffff0000u); }

__device__ inline void gload16(const unsigned short* g, unsigned short* l) {
    __builtin_amdgcn_global_load_lds((const uint_as1*)g, (uint_as3*)l, 16, 0, 0);
}

// Read one MFMA A/B fragment from a swizzled 128x128 LDS tile.
// Tile = two 64-wide sub-tiles; slot(row, chunk) = row*64 + (chunk^(row&7))*8.
__device__ inline bf16x8 ldfrag(const unsigned short* t, int row, int ks, int quad) {
    int ch = (ks & 1) * 4 + quad;
    int pos = ch ^ (row & 7);
    return *(const bf16x8*)&t[((ks >> 1) << 13) + row * 64 + pos * 8];
}

// ------------------------------- CSR build ---------------------------------

__global__ void k_zero(int* __restrict__ p, int n) {
    int i = blockIdx.x * 256 + threadIdx.x;
    if (i < n) p[i] = 0;
}

__global__ void k_count(const int* __restrict__ ei, int* __restrict__ counts,
                        int E, int N) {
    int e = blockIdx.x * 256 + threadIdx.x;
    if (e >= E + N) return;
    int col = (e < E) ? ei[E + e] : (e - E);
    atomicAdd(&counts[col], 1);
}

__global__ void k_scan1(const int* __restrict__ counts, int* __restrict__ incl,
                        int* __restrict__ bsums, int N) {
    __shared__ int s[256];
    int t = threadIdx.x, i = blockIdx.x * 256 + t;
    int v = (i < N) ? counts[i] : 0;
    s[t] = v; __syncthreads();
    for (int off = 1; off < 256; off <<= 1) {
        int add = (t >= off) ? s[t - off] : 0;
        __syncthreads();
        s[t] += add;
        __syncthreads();
    }
    if (i < N) incl[i] = s[t];
    if (t == 255) bsums[blockIdx.x] = s[255];
}

__global__ void k_scan2(const int* __restrict__ bsums, int* __restrict__ boffs, int NB) {
    __shared__ int s[256];
    int t = threadIdx.x;
    int v = (t < NB) ? bsums[t] : 0;
    s[t] = v; __syncthreads();
    for (int off = 1; off < 256; off <<= 1) {
        int add = (t >= off) ? s[t - off] : 0;
        __syncthreads();
        s[t] += add;
        __syncthreads();
    }
    if (t < NB) boffs[t] = s[t] - v;   // exclusive
}

__global__ void k_scan3(const int* __restrict__ incl, const int* __restrict__ counts,
                        const int* __restrict__ boffs, int* __restrict__ nstart,
                        int* __restrict__ cursor, int N) {
    int i = blockIdx.x * 256 + threadIdx.x;
    if (i >= N) return;
    int st = incl[i] - counts[i] + boffs[blockIdx.x];
    nstart[i] = st;
    cursor[i] = st;
}

__global__ void k_fill(const int* __restrict__ ei, int* __restrict__ cursor,
                       int* __restrict__ csr, int E, int N) {
    int e = blockIdx.x * 256 + threadIdx.x;
    if (e >= E + N) return;
    int row, col;
    if (e < E) { row = ei[e]; col = ei[E + e]; }
    else       { row = col = e - E; }
    int pos = atomicAdd(&cursor[col], 1);
    csr[pos] = row;
}

// ------------------------------ prep (casts) -------------------------------

__global__ void k_cast(const float* __restrict__ x, unsigned short* __restrict__ xb,
                       int total4) {
    int i = blockIdx.x * 256 + threadIdx.x;
    if (i >= total4) return;
    float4 v = ((const float4*)x)[i];
    ushort4 o;
    o.x = f2bf(v.x); o.y = f2bf(v.y); o.z = f2bf(v.z); o.w = f2bf(v.w);
    ((ushort4*)xb)[i] = o;
}

// transpose fp32 [K][Co] -> bf16 [Co][K].  Wq/Wk/Wv land contiguously.
__global__ void k_prep(const float* Wq, const float* Wk, const float* Wv, const float* Wo,
                       const float* Wf1, const float* Wf2,
                       unsigned short* Wqkvt, unsigned short* Wot,
                       unsigned short* Wf1t, unsigned short* Wf2t) {
    int z = blockIdx.y;
    const float* in; unsigned short* out; int K, Co;
    switch (z) {
        case 0: in = Wq;  out = Wqkvt;          K = 128; Co = 128; break;
        case 1: in = Wk;  out = Wqkvt + 16384;  K = 128; Co = 128; break;
        case 2: in = Wv;  out = Wqkvt + 32768;  K = 128; Co = 128; break;
        case 3: in = Wo;  out = Wot;            K = 128; Co = 128; break;
        case 4: in = Wf1; out = Wf1t;           K = 128; Co = 512; break;
        default: in = Wf2; out = Wf2t;          K = 512; Co = 128; break;
    }
    int idx = blockIdx.x * 256 + threadIdx.x;
    if (idx >= K * Co) return;
    int k = idx / Co, c = idx % Co;
    out[c * K + k] = f2bf(in[idx]);
}

// ------------------- K=128 GEMM, single barrier ----------------------------
// Block: 128 rows x 128 cols; 4 waves 2x2, 64x64 each (16 accs).
// A staged to LDS (one shot); B-frags streamed from global (L2-hot weights).
// EPI 0: store bf16 at [row*Cout + n0+col].
// EPI 2 (Cout=128): +bias+resid, LN over 128 cols -> outf fp32 + outb bf16.

template <int EPI>
__global__ __launch_bounds__(256) void k_gemm128(
    const unsigned short* __restrict__ A, const unsigned short* __restrict__ Bt,
    const float* __restrict__ bias, const float* __restrict__ resid,
    const float* __restrict__ g, const float* __restrict__ b,
    float* __restrict__ outf, unsigned short* __restrict__ outb,
    int M, int Cout) {
    __shared__ unsigned short As[16384];
    __shared__ float pSum[2][128];
    __shared__ float pSq[2][128];

    int tid = threadIdx.x;
    int wid = tid >> 6, lane = tid & 63;
    int quad = lane >> 4, l16 = lane & 15;
    int wr = wid >> 1, wc = wid & 1;
    int m0 = blockIdx.x * 128;
    int n0 = blockIdx.y * 128;

    int rsub = lane >> 3, ch = lane & 7;
    int gch = ch ^ rsub;                 // row&7 == rsub
#pragma unroll
    for (int kt = 0; kt < 2; ++kt)
#pragma unroll
        for (int j = 0; j < 4; ++j) {
            int row = j * 32 + wid * 8 + rsub;
            int ra = m0 + row; if (ra > M - 1) ra = M - 1;
            gload16(A + (size_t)ra * 128 + kt * 64 + gch * 8,
                    As + kt * 8192 + j * 2048 + wid * 512 + lane * 8);
        }
    __syncthreads();

    const bf16x8* Brow[4];
#pragma unroll
    for (int tj = 0; tj < 4; ++tj)
        Brow[tj] = (const bf16x8*)(Bt + (size_t)(n0 + wc * 64 + tj * 16 + l16) * 128);

    f32x4 acc[4][4];
#pragma unroll
    for (int i = 0; i < 4; ++i)
#pragma unroll
        for (int j = 0; j < 4; ++j) acc[i][j] = {0.f, 0.f, 0.f, 0.f};

#pragma unroll
    for (int ks = 0; ks < 4; ++ks) {
        bf16x8 af[4], bfr[4];
#pragma unroll
        for (int t4 = 0; t4 < 4; ++t4)
            af[t4] = ldfrag(As, wr * 64 + t4 * 16 + l16, ks, quad);
#pragma unroll
        for (int tj = 0; tj < 4; ++tj)
            bfr[tj] = Brow[tj][ks * 4 + quad];
#pragma unroll
        for (int ti = 0; ti < 4; ++ti)
#pragma unroll
            for (int tj = 0; tj < 4; ++tj)
                acc[ti][tj] = __builtin_amdgcn_mfma_f32_16x16x32_bf16(
                    af[ti], bfr[tj], acc[ti][tj], 0, 0, 0);
    }

    if constexpr (EPI != 2) {
#pragma unroll
        for (int ti = 0; ti < 4; ++ti)
#pragma unroll
            for (int tj = 0; tj < 4; ++tj) {
                int col = n0 + wc * 64 + tj * 16 + l16;
#pragma unroll
                for (int r = 0; r < 4; ++r) {
                    int row = m0 + wr * 64 + ti * 16 + quad * 4 + r;
                    if (row >= M) continue;
                    outb[(size_t)row * Cout + col] = f2bf(acc[ti][tj][r]);
                }
            }
    } else {
        float bi[4], gv[4], bv[4];
#pragma unroll
        for (int tj = 0; tj < 4; ++tj) {
            int col = wc * 64 + tj * 16 + l16;
            bi[tj] = bias[col]; gv[tj] = g[col]; bv[tj] = b[col];
        }
#pragma unroll
        for (int ti = 0; ti < 4; ++ti)
#pragma unroll
            for (int tj = 0; tj < 4; ++tj) {
                int col = wc * 64 + tj * 16 + l16;
#pragma unroll
                for (int r = 0; r < 4; ++r) {
                    int row = m0 + wr * 64 + ti * 16 + quad * 4 + r;
                    float rv = (row < M) ? resid[(size_t)row * 128 + col] : 0.f;
                    acc[ti][tj][r] += bi[tj] + rv;
                }
            }
#pragma unroll
        for (int ti = 0; ti < 4; ++ti)
#pragma unroll
            for (int r = 0; r < 4; ++r) {
                float s = acc[ti][0][r] + acc[ti][1][r] + acc[ti][2][r] + acc[ti][3][r];
                float q = acc[ti][0][r] * acc[ti][0][r] + acc[ti][1][r] * acc[ti][1][r]
                        + acc[ti][2][r] * acc[ti][2][r] + acc[ti][3][r] * acc[ti][3][r];
                s += __shfl_xor(s, 1); q += __shfl_xor(q, 1);
                s += __shfl_xor(s, 2); q += __shfl_xor(q, 2);
                s += __shfl_xor(s, 4); q += __shfl_xor(q, 4);
                s += __shfl_xor(s, 8); q += __shfl_xor(q, 8);
                if (l16 == 0) {
                    int lr = wr * 64 + ti * 16 + quad * 4 + r;
                    pSum[wc][lr] = s; pSq[wc][lr] = q;
                }
            }
        __syncthreads();
        if (tid < 128) {
            float s = pSum[0][tid] + pSum[1][tid];
            float q = pSq[0][tid] + pSq[1][tid];
            float mean = s * 0.0078125f;
            float var = q * 0.0078125f - mean * mean;
            pSum[0][tid] = mean;
            pSq[0][tid] = rsqrtf(var + 1e-5f);
        }
        __syncthreads();
#pragma unroll
        for (int ti = 0; ti < 4; ++ti)
#pragma unroll
            for (int r = 0; r < 4; ++r) {
                int lr = wr * 64 + ti * 16 + quad * 4 + r;
                int row = m0 + lr;
                if (row >= M) continue;
                float mean = pSum[0][lr], rs = pSq[0][lr];
#pragma unroll
                for (int tj = 0; tj < 4; ++tj) {
                    int col = wc * 64 + tj * 16 + l16;
                    float y = (acc[ti][tj][r] - mean) * rs * gv[tj] + bv[tj];
                    if (outf) outf[(size_t)row * 128 + col] = y;
                    if (outb) outb[(size_t)row * 128 + col] = f2bf(y);
                }
            }
    }
}

// --------------------------- fused FFN + LN2 -------------------------------
// Block (512 thr, 8 waves 2x4): 128 rows. x1 tile in LDS (As). For each of
// 4 hidden chunks (128): GEMM1 (B=Wf1 from global) -> gelu -> Hs (LDS,
// swizzled A-layout) -> GEMM2 (B=Wf2 from global) accumulates out.
// Epilogue: +bf2 + resid(x1f) + LN2 -> d_out fp32. Wave tile 64x32 (8 accs).

__global__ __launch_bounds__(512) void k_ffn(
    const unsigned short* __restrict__ x1b, const unsigned short* __restrict__ Wf1t,
    const float* __restrict__ bf1, const unsigned short* __restrict__ Wf2t,
    const float* __restrict__ bf2, const float* __restrict__ x1f,
    const float* __restrict__ g2, const float* __restrict__ b2,
    float* __restrict__ outp, int M) {
    __shared__ unsigned short As[16384];
    __shared__ unsigned short Hs[16384];

    int tid = threadIdx.x;
    int wid = tid >> 6, lane = tid & 63;
    int quad = lane >> 4, l16 = lane & 15;
    int wr = wid >> 2;           // 0..1 (row half)
    int wc = wid & 3;            // 0..3 (col quarter)
    int m0 = blockIdx.x * 128;

    // stage x1 tile (32 KB): 512 threads, 2 kt x 2 j rounds
    int rsub = lane >> 3, ch = lane & 7;
    int gch = ch ^ rsub;
#pragma unroll
    for (int kt = 0; kt < 2; ++kt)
#pragma unroll
        for (int j = 0; j < 2; ++j) {
            int row = j * 64 + wid * 8 + rsub;
            int ra = m0 + row; if (ra > M - 1) ra = M - 1;
            gload16(x1b + (size_t)ra * 128 + kt * 64 + gch * 8,
                    As + kt * 8192 + j * 4096 + wid * 512 + lane * 8);
        }

    f32x4 oacc[4][2];
#pragma unroll
    for (int i = 0; i < 4; ++i) { oacc[i][0] = {0.f,0.f,0.f,0.f}; oacc[i][1] = oacc[i][0]; }

    for (int c = 0; c < 4; ++c) {
        __syncthreads();   // c==0: As staged; c>0: prev G2 done reading Hs
        // ---- GEMM1: h_chunk[128 rows][128 hcols] ----
        f32x4 hacc[4][2];
#pragma unroll
        for (int i = 0; i < 4; ++i) { hacc[i][0] = {0.f,0.f,0.f,0.f}; hacc[i][1] = hacc[i][0]; }
        const bf16x8* B1row[2];
#pragma unroll
        for (int u = 0; u < 2; ++u)
            B1row[u] = (const bf16x8*)(Wf1t + (size_t)(c * 128 + wc * 32 + u * 16 + l16) * 128);
#pragma unroll
        for (int ks = 0; ks < 4; ++ks) {
            bf16x8 af[4], bfr[2];
#pragma unroll
            for (int t4 = 0; t4 < 4; ++t4)
                af[t4] = ldfrag(As, wr * 64 + t4 * 16 + l16, ks, quad);
#pragma unroll
            for (int u = 0; u < 2; ++u) bfr[u] = B1row[u][ks * 4 + quad];
#pragma unroll
            for (int t4 = 0; t4 < 4; ++t4)
#pragma unroll
                for (int u = 0; u < 2; ++u)
                    hacc[t4][u] = __builtin_amdgcn_mfma_f32_16x16x32_bf16(
                        af[t4], bfr[u], hacc[t4][u], 0, 0, 0);
        }
        // ---- gelu -> Hs (C-layout -> swizzled A-layout) ----
        float b1v[2];
#pragma unroll
        for (int u = 0; u < 2; ++u) b1v[u] = bf1[c * 128 + wc * 32 + u * 16 + l16];
#pragma unroll
        for (int t4 = 0; t4 < 4; ++t4)
#pragma unroll
            for (int u = 0; u < 2; ++u) {
                int k = wc * 32 + u * 16 + l16;
                int kt = k >> 6, kk = k & 63;
#pragma unroll
                for (int r = 0; r < 4; ++r) {
                    int row = wr * 64 + t4 * 16 + quad * 4 + r;
                    float gg = hacc[t4][u][r] + b1v[u];
                    float y = 0.5f * gg * (1.f + erff(gg * 0.70710678118f));
                    int pos = (kk >> 3) ^ (row & 7);
                    Hs[kt * 8192 + row * 64 + pos * 8 + (kk & 7)] = f2bf(y);
                }
            }
        __syncthreads();   // Hs complete
        // ---- GEMM2: out += Hs @ Wf2[chunk] ----
        const bf16x8* B2row[2];
#pragma unroll
        for (int u = 0; u < 2; ++u)
            B2row[u] = (const bf16x8*)(Wf2t + (size_t)(wc * 32 + u * 16 + l16) * 512 + c * 128);
#pragma unroll
        for (int ks = 0; ks < 4; ++ks) {
            bf16x8 af[4], bfr[2];
#pragma unroll
            for (int t4 = 0; t4 < 4; ++t4)
                af[t4] = ldfrag(Hs, wr * 64 + t4 * 16 + l16, ks, quad);
#pragma unroll
            for (int u = 0; u < 2; ++u) bfr[u] = B2row[u][ks * 4 + quad];
#pragma unroll
            for (int t4 = 0; t4 < 4; ++t4)
#pragma unroll
                for (int u = 0; u < 2; ++u)
                    oacc[t4][u] = __builtin_amdgcn_mfma_f32_16x16x32_bf16(
                        af[t4], bfr[u], oacc[t4][u], 0, 0, 0);
        }
    }
    __syncthreads();       // all Hs reads done; alias Hs for LN arrays
    float* pS = (float*)Hs;            // [4][128]
    float* pQ = pS + 512;              // [4][128]
    float* mv = pQ + 512;              // mean[128], rstd[128]

    float b2v[2], gv[2], bv[2];
#pragma unroll
    for (int u = 0; u < 2; ++u) {
        int col = wc * 32 + u * 16 + l16;
        b2v[u] = bf2[col]; gv[u] = g2[col]; bv[u] = b2[col];
    }
#pragma unroll
    for (int t4 = 0; t4 < 4; ++t4)
#pragma unroll
        for (int u = 0; u < 2; ++u) {
            int col = wc * 32 + u * 16 + l16;
#pragma unroll
            for (int r = 0; r < 4; ++r) {
                int row = m0 + wr * 64 + t4 * 16 + quad * 4 + r;
                float rv = (row < M) ? x1f[(size_t)row * 128 + col] : 0.f;
                oacc[t4][u][r] += b2v[u] + rv;
            }
        }
#pragma unroll
    for (int t4 = 0; t4 < 4; ++t4)
#pragma unroll
        for (int r = 0; r < 4; ++r) {
            int lr = wr * 64 + t4 * 16 + quad * 4 + r;
            float s = oacc[t4][0][r] + oacc[t4][1][r];
            float q = oacc[t4][0][r] * oacc[t4][0][r] + oacc[t4][1][r] * oacc[t4][1][r];
            s += __shfl_xor(s, 1); q += __shfl_xor(q, 1);
            s += __shfl_xor(s, 2); q += __shfl_xor(q, 2);
            s += __shfl_xor(s, 4); q += __shfl_xor(q, 4);
            s += __shfl_xor(s, 8); q += __shfl_xor(q, 8);
            if (l16 == 0) { pS[wc * 128 + lr] = s; pQ[wc * 128 + lr] = q; }
        }
    __syncthreads();
    if (tid < 128) {
        float s = pS[tid] + pS[128 + tid] + pS[256 + tid] + pS[384 + tid];
        float q = pQ[tid] + pQ[128 + tid] + pQ[256 + tid] + pQ[384 + tid];
        float mean = s * 0.0078125f;
        float var = q * 0.0078125f - mean * mean;
        mv[tid] = mean;
        mv[128 + tid] = rsqrtf(var + 1e-5f);
    }
    __syncthreads();
#pragma unroll
    for (int t4 = 0; t4 < 4; ++t4)
#pragma unroll
        for (int r = 0; r < 4; ++r) {
            int lr = wr * 64 + t4 * 16 + quad * 4 + r;
            int row = m0 + lr;
            if (row >= M) continue;
            float mean = mv[lr], rs = mv[128 + lr];
#pragma unroll
            for (int u = 0; u < 2; ++u) {
                int col = wc * 32 + u * 16 + l16;
                outp[(size_t)row * 128 + col] = (oacc[t4][u][r] - mean) * rs * gv[u] + bv[u];
            }
        }
}

// ------------------------------ attention ----------------------------------
// One wave per destination node j; qkv row = [q|k|v] (192 dwords). Lane l
// owns channels (2l,2l+1); lanes 8h..8h+7 hold head h -> 3 shfl_xor reduce.
// 4-edge batches: 8 gathers in flight, one batched online-softmax update.

__global__ __launch_bounds__(256) void k_attn(
    const unsigned int* __restrict__ qkv, const int* __restrict__ nstart,
    const int* __restrict__ counts, const int* __restrict__ csr,
    unsigned int* __restrict__ ob, int N) {
    int j = blockIdx.x * 4 + (threadIdx.x >> 6);
    if (j >= N) return;
    int l = threadIdx.x & 63;

    unsigned int kw = qkv[(size_t)j * 192 + 64 + l];
    float kx = bflo(kw), ky = bfhi(kw);

    int start = nstart[j], cnt = counts[j];
    float m = -3.0e38f, lsum = 0.f, a0 = 0.f, a1 = 0.f;
    int i = 0;
    for (; i + 4 <= cnt; i += 4) {
        int r0 = csr[start + i + 0], r1 = csr[start + i + 1];
        int r2 = csr[start + i + 2], r3 = csr[start + i + 3];
        unsigned int qw0 = qkv[(size_t)r0 * 192 + l];
        unsigned int qw1 = qkv[(size_t)r1 * 192 + l];
        unsigned int qw2 = qkv[(size_t)r2 * 192 + l];
        unsigned int qw3 = qkv[(size_t)r3 * 192 + l];
        unsigned int vw0 = qkv[(size_t)r0 * 192 + 128 + l];
        unsigned int vw1 = qkv[(size_t)r1 * 192 + 128 + l];
        unsigned int vw2 = qkv[(size_t)r2 * 192 + 128 + l];
        unsigned int vw3 = qkv[(size_t)r3 * 192 + 128 + l];

        float p0 = fmaf(bflo(qw0), kx, bfhi(qw0) * ky);
        float p1 = fmaf(bflo(qw1), kx, bfhi(qw1) * ky);
        float p2 = fmaf(bflo(qw2), kx, bfhi(qw2) * ky);
        float p3 = fmaf(bflo(qw3), kx, bfhi(qw3) * ky);
        p0 += __shfl_xor(p0, 1); p1 += __shfl_xor(p1, 1);
        p2 += __shfl_xor(p2, 1); p3 += __shfl_xor(p3, 1);
        p0 += __shfl_xor(p0, 2); p1 += __shfl_xor(p1, 2);
        p2 += __shfl_xor(p2, 2); p3 += __shfl_xor(p3, 2);
        p0 += __shfl_xor(p0, 4); p1 += __shfl_xor(p1, 4);
        p2 += __shfl_xor(p2, 4); p3 += __shfl_xor(p3, 4);
        float s0 = p0 * 0.25f, s1 = p1 * 0.25f, s2 = p2 * 0.25f, s3 = p3 * 0.25f;

        float mn = fmaxf(fmaxf(fmaxf(s0, s1), fmaxf(s2, s3)), m);
        float scale = __expf(m - mn);
        float e0 = __expf(s0 - mn), e1 = __expf(s1 - mn);
        float e2 = __expf(s2 - mn), e3 = __expf(s3 - mn);
        lsum = lsum * scale + ((e0 + e1) + (e2 + e3));
        a0 = a0 * scale + e0 * bflo(vw0) + e1 * bflo(vw1) + e2 * bflo(vw2) + e3 * bflo(vw3);
        a1 = a1 * scale + e0 * bfhi(vw0) + e1 * bfhi(vw1) + e2 * bfhi(vw2) + e3 * bfhi(vw3);
        m = mn;
    }
    for (; i < cnt; ++i) {
        int r = csr[start + i];
        unsigned int qw = qkv[(size_t)r * 192 + l];
        unsigned int vw = qkv[(size_t)r * 192 + 128 + l];
        float p = fmaf(bflo(qw), kx, bfhi(qw) * ky);
        p += __shfl_xor(p, 1);
        p += __shfl_xor(p, 2);
        p += __shfl_xor(p, 4);
        float sc = p * 0.25f;
        float mn = fmaxf(m, sc);
        float scale = __expf(m - mn);
        float e = __expf(sc - mn);
        lsum = lsum * scale + e;
        a0 = a0 * scale + e * bflo(vw);
        a1 = a1 * scale + e * bfhi(vw);
        m = mn;
    }
    float inv = 1.f / (lsum + 1e-8f);
    unsigned int w = ((unsigned int)f2bf(a1 * inv) << 16) | (unsigned int)f2bf(a0 * inv);
    ob[(size_t)j * 64 + l] = w;
}

// -------------------------------- launch -----------------------------------

extern "C" void kernel_launch(void* const* d_in, const int* in_sizes, int n_in,
                              void* d_out, int out_size, void* d_ws, size_t ws_size,
                              hipStream_t stream) {
    const float* x   = (const float*)d_in[0];
    const int* ei    = (const int*)d_in[1];      // int64 materialized as int32
    const float* Wq  = (const float*)d_in[2];
    const float* Wk  = (const float*)d_in[3];
    const float* Wv  = (const float*)d_in[4];
    const float* Wo  = (const float*)d_in[5];
    const float* bo  = (const float*)d_in[6];
    const float* Wf1 = (const float*)d_in[7];
    const float* bf1 = (const float*)d_in[8];
    const float* Wf2 = (const float*)d_in[9];
    const float* bf2 = (const float*)d_in[10];
    const float* g1  = (const float*)d_in[11];
    const float* b1  = (const float*)d_in[12];
    const float* g2  = (const float*)d_in[13];
    const float* b2  = (const float*)d_in[14];

    int N = in_sizes[0] / 128;
    int E = in_sizes[1] / 2;
    int N2 = ((N + 127) / 128) * 128;
    int NE = E + N;

    char* p = (char*)d_ws;
    auto alloc = [&](size_t bytes) -> char* {
        char* r = p;
        p += (bytes + 255) & ~(size_t)255;
        return r;
    };
    // R0: [qkv (N2*384) | ob (N2*128)] bf16.
    unsigned short* qkv = (unsigned short*)alloc((size_t)N2 * 512 * 2);
    unsigned short* ob  = qkv + (size_t)N2 * 384;
    // xb aliases x1b: xb dead after QKV GEMM; x1b first written by Wo-LN.
    unsigned short* x1b = (unsigned short*)alloc((size_t)N2 * 128 * 2);
    unsigned short* xb  = x1b;                   // alias
    float* x1f          = (float*)alloc((size_t)N2 * 128 * 4);
    unsigned short* Wqkvt = (unsigned short*)alloc(3 * 128 * 128 * 2);
    unsigned short* Wot   = (unsigned short*)alloc(128 * 128 * 2);
    unsigned short* Wf1t  = (unsigned short*)alloc(512 * 128 * 2);
    unsigned short* Wf2t  = (unsigned short*)alloc(128 * 512 * 2);
    int* counts = (int*)alloc((size_t)N * 4);
    int* incl   = (int*)alloc((size_t)N * 4);
    int* nstart = (int*)alloc((size_t)N * 4);
    int* cursor = (int*)alloc((size_t)N * 4);
    int* bsums  = (int*)alloc(1024 * 4);
    int* boffs  = (int*)alloc(1024 * 4);
    int* csr    = (int*)alloc((size_t)NE * 4);

    int NB = (N + 255) / 256;          // 196 (<256, one-block scan2)
    int M128 = (N + 127) / 128;        // 391

    k_zero<<<NB, 256, 0, stream>>>(counts, N);
    k_count<<<(NE + 255) / 256, 256, 0, stream>>>(ei, counts, E, N);
    k_scan1<<<NB, 256, 0, stream>>>(counts, incl, bsums, N);
    k_scan2<<<1, 256, 0, stream>>>(bsums, boffs, NB);
    k_scan3<<<NB, 256, 0, stream>>>(incl, counts, boffs, nstart, cursor, N);
    k_fill<<<(NE + 255) / 256, 256, 0, stream>>>(ei, cursor, csr, E, N);

    k_cast<<<((N * 128 / 4) + 255) / 256, 256, 0, stream>>>(x, xb, N * 128 / 4);
    k_prep<<<dim3(256, 6), 256, 0, stream>>>(Wq, Wk, Wv, Wo, Wf1, Wf2,
                                             Wqkvt, Wot, Wf1t, Wf2t);

    // QKV: A=xb [N][128], Bt=Wqkvt [384][128] -> qkv [N][384]
    k_gemm128<0><<<dim3(M128, 3), 256, 0, stream>>>(
        xb, Wqkvt, nullptr, nullptr, nullptr, nullptr, nullptr, qkv, N, 384);

    k_attn<<<(N + 3) / 4, 256, 0, stream>>>((const unsigned int*)qkv, nstart,
                                            counts, csr, (unsigned int*)ob, N);

    // Wo + bias + residual(x) + LN1 -> x1f (fp32), x1b (bf16)
    k_gemm128<2><<<dim3(M128, 1), 256, 0, stream>>>(
        ob, Wot, bo, x, g1, b1, x1f, x1b, N, 128);

    // fused FFN1 + gelu + FFN2 + bias + residual + LN2 -> d_out
    k_ffn<<<dim3(M128), 512, 0, stream>>>(
        x1b, Wf1t, bf1, Wf2t, bf2, x1f, g2, b2, (float*)d_out, N);
}